// Round 4
// baseline (569.390 us; speedup 1.0000x reference)
//
#include <hip/hip_runtime.h>

typedef unsigned short u16;
typedef unsigned int u32;
typedef short bf16x8 __attribute__((ext_vector_type(8)));
typedef float f32x4 __attribute__((ext_vector_type(4)));
typedef unsigned short u16x8 __attribute__((ext_vector_type(8)));

#define DEVFN static __device__ __forceinline__

DEVFN u16 f2b(float f) {
    u32 u = __builtin_bit_cast(u32, f);
    u += 0x7FFFu + ((u >> 16) & 1u);
    return (u16)(u >> 16);
}
DEVFN float b2f(u16 h) {
    u32 u = ((u32)h) << 16;
    return __builtin_bit_cast(float, u);
}

// ---------------------------------------------------------------- prep ----
__global__ void k_prep(const float* __restrict__ qkvw, const float* __restrict__ pjw,
                       u16* __restrict__ qkvwb, u16* __restrict__ pjwb) {
    int id = blockIdx.x * 256 + threadIdx.x;
    if (id < 196608) qkvwb[id] = f2b(qkvw[id]);
    if (id < 65536)  pjwb[id]  = f2b(pjw[id]);
}

__global__ void k_cpb(const float* __restrict__ w1, const float* __restrict__ b1,
                      const float* __restrict__ w2, float* __restrict__ bt) {
    int p = threadIdx.x;
    if (p >= 225) return;
    int d0 = p / 15, d1 = p % 15;
    float v0 = (float)(d0 - 7) * (8.0f / 7.0f);
    float v1 = (float)(d1 - 7) * (8.0f / 7.0f);
    float t0 = copysignf(log2f(fabsf(v0) + 1.0f) * (1.0f / 3.0f), v0);
    float t1 = copysignf(log2f(fabsf(v1) + 1.0f) * (1.0f / 3.0f), v1);
    float s[8] = {0.f, 0.f, 0.f, 0.f, 0.f, 0.f, 0.f, 0.f};
    for (int d = 0; d < 256; ++d) {
        float h = t0 * w1[2 * d] + t1 * w1[2 * d + 1] + b1[d];
        h = fmaxf(h, 0.0f);
        #pragma unroll
        for (int hh = 0; hh < 8; ++hh) s[hh] += h * w2[hh * 256 + d];
    }
    #pragma unroll
    for (int hh = 0; hh < 8; ++hh) bt[p * 8 + hh] = s[hh];
}

__global__ void k_bias(const float* __restrict__ bt, float* __restrict__ bias) {
    int id = blockIdx.x * 256 + threadIdx.x;  // 4096 = 64*64, i=q row, j=k col
    int i = id >> 6, j = id & 63;
    int d0 = (i >> 3) - (j >> 3) + 7;
    int d1 = (i & 7) - (j & 7) + 7;
    int p = d0 * 15 + d1;
    #pragma unroll
    for (int h = 0; h < 8; ++h)
        bias[h * 4096 + id] = 16.0f / (1.0f + expf(-bt[p * 8 + h]));
}

// ---------------------------------------------------------------- qkv -----
// Row-structured GEMM: block = (image row, which, och-half). M=128 tokens
// (one row), N=128 och, K=256 chunked at 64 with double-buffered LDS.
// Transpose happens on the LDS write side with packed u16x8 writes.
// Outputs qn/kn -> [win][h][tok][32], v -> wv [win*64+tok][256] (R1 layouts).
__global__ __launch_bounds__(256, 4) void k_qkv(
    const float* __restrict__ x, const u16* __restrict__ qkvw,
    const float* __restrict__ qkvb,
    u16* __restrict__ gq, u16* __restrict__ gk, u16* __restrict__ wv_g) {
    __shared__ __align__(16) u16 Xs[2][8192];  // [128 tok][64 ch] swizzled

    // XCD-aware job mapping: all 6 (which,half) blocks of a row on one XCD.
    const int bid = blockIdx.x;                 // 6144 = 8 xcd * 128 rowblk * 6 ny
    const int xcd = bid & 7;
    const int idx = bid >> 3;                   // 0..767
    const int ny = idx % 6;
    const int rowblk = xcd * 128 + idx / 6;     // 0..1023
    const int b = rowblk >> 7, row = rowblk & 127;
    const int which = ny >> 1, half = ny & 1;

    const int tid = threadIdx.x;
    const int wave = tid >> 6, l = tid & 63, col = l & 15, quad = l >> 4;
    const int th = wave >> 1;                   // token half (64 tok)
    const int oq = wave & 1;                    // och quarter
    const int obase = half * 128 + oq * 64;     // och base within `which` (0..255)

    // weight rows + bias for this wave's 4 n-tiles (original qkvw layout)
    int orow[4];
    float bq[4];
    #pragma unroll
    for (int nt = 0; nt < 4; ++nt) {
        const int oo = obase + nt * 16 + col;   // 0..255 within which
        orow[nt] = (oo >> 5) * 96 + which * 32 + (oo & 31);
        bq[nt] = qkvb[orow[nt]];
    }

    const int tc = tid >> 5;                    // 0..7: 8-ch sub-chunk
    const int tw = (tid & 31) * 4;              // token base (4 consecutive)
    const float* xbase = x + ((size_t)b * 256 * 128 + row) * 128;

    f32x4 acc[4][4];
    #pragma unroll
    for (int i = 0; i < 4; ++i)
        #pragma unroll
        for (int j = 0; j < 4; ++j) acc[i][j] = f32x4{0.f, 0.f, 0.f, 0.f};

    float4 st[8];
    auto stage_load = [&](int c) {
        #pragma unroll
        for (int j = 0; j < 8; ++j)
            st[j] = *(const float4*)(xbase + (size_t)(c * 64 + tc * 8 + j) * 16384 + tw);
    };
    auto stage_write = [&](int buf) {
        #pragma unroll
        for (int i = 0; i < 4; ++i) {
            const int tok = tw + i;
            const int slot = tc ^ (((tok >> 2) ^ tok) & 7);
            u16x8 v;
            #pragma unroll
            for (int j = 0; j < 8; ++j) v[j] = f2b(((const float*)&st[j])[i]);
            *(u16x8*)&Xs[buf][tok * 64 + (slot << 3)] = v;
        }
    };
    auto gemm = [&](int c, int buf) {
        #pragma unroll
        for (int kk = 0; kk < 2; ++kk) {
            const int cb = c * 64 + kk * 32 + quad * 8;   // global ch base
            const int lchunk = kk * 4 + quad;             // local 8-ch chunk
            bf16x8 bw[4];
            #pragma unroll
            for (int nt = 0; nt < 4; ++nt)
                bw[nt] = *(const bf16x8*)&qkvw[(size_t)orow[nt] * 256 + cb];
            bf16x8 af[4];
            #pragma unroll
            for (int mt = 0; mt < 4; ++mt) {
                const int tok = th * 64 + mt * 16 + col;
                const int slot = lchunk ^ (((tok >> 2) ^ tok) & 7);
                af[mt] = *(const bf16x8*)&Xs[buf][tok * 64 + (slot << 3)];
            }
            #pragma unroll
            for (int mt = 0; mt < 4; ++mt)
                #pragma unroll
                for (int nt = 0; nt < 4; ++nt)
                    acc[mt][nt] = __builtin_amdgcn_mfma_f32_16x16x32_bf16(
                        af[mt], bw[nt], acc[mt][nt], 0, 0, 0);
        }
    };

    stage_load(0);
    stage_write(0);
    __syncthreads();
    for (int c = 0; c < 4; ++c) {
        if (c < 3) stage_load(c + 1);      // issue early (T14)
        gemm(c, c & 1);
        if (c < 3) stage_write((c + 1) & 1);  // write late
        __syncthreads();
    }

    // epilogue: +bias; cosine-norm (q/k) over d via 16-lane shfl_xor (R1 math)
    const int hA = obase >> 5;  // first of the two heads this wave covers
    #pragma unroll
    for (int mt = 0; mt < 4; ++mt) {
        float v0[4], v1[4], v2[4], v3[4];
        #pragma unroll
        for (int r = 0; r < 4; ++r) {
            v0[r] = acc[mt][0][r] + bq[0];
            v1[r] = acc[mt][1][r] + bq[1];
            v2[r] = acc[mt][2][r] + bq[2];
            v3[r] = acc[mt][3][r] + bq[3];
        }
        if (which < 2) {
            float s0[4], s1[4];
            #pragma unroll
            for (int r = 0; r < 4; ++r) {
                s0[r] = v0[r] * v0[r] + v1[r] * v1[r];
                s1[r] = v2[r] * v2[r] + v3[r] * v3[r];
            }
            #pragma unroll
            for (int m = 1; m < 16; m <<= 1) {
                #pragma unroll
                for (int r = 0; r < 4; ++r) {
                    s0[r] += __shfl_xor(s0[r], m, 64);
                    s1[r] += __shfl_xor(s1[r], m, 64);
                }
            }
            #pragma unroll
            for (int r = 0; r < 4; ++r) {
                const float i0 = 1.0f / fmaxf(sqrtf(s0[r]), 1e-12f);
                const float i1 = 1.0f / fmaxf(sqrtf(s1[r]), 1e-12f);
                v0[r] *= i0; v1[r] *= i0;
                v2[r] *= i1; v3[r] *= i1;
            }
        }
        #pragma unroll
        for (int r = 0; r < 4; ++r) {
            const int w = th * 64 + mt * 16 + quad * 4 + r;      // token in row
            const int win = b * 256 + (row >> 3) * 16 + (w >> 3);
            const int tk = (row & 7) * 8 + (w & 7);
            if (which == 2) {
                u16* wvp = wv_g + ((size_t)win * 64 + tk) * 256 + obase;
                wvp[col]      = f2b(v0[r]);
                wvp[col + 16] = f2b(v1[r]);
                wvp[col + 32] = f2b(v2[r]);
                wvp[col + 48] = f2b(v3[r]);
            } else {
                u16* G = (which == 0) ? gq : gk;
                const size_t baseA = ((size_t)(win * 8 + hA) * 64 + tk) * 32;
                const size_t baseB = ((size_t)(win * 8 + hA + 1) * 64 + tk) * 32;
                G[baseA + col]      = f2b(v0[r]);
                G[baseA + col + 16] = f2b(v1[r]);
                G[baseB + col]      = f2b(v2[r]);
                G[baseB + col + 16] = f2b(v3[r]);
            }
        }
    }
}

// ---------------------------------------------------------------- attn ----
// R3 verbatim: one wave = one (win, head); 4 jobs per 256-thr block.
__global__ __launch_bounds__(256, 3) void k_attn3(
    const u16* __restrict__ gq, const u16* __restrict__ gk,
    const u16* __restrict__ wv_g,
    const float* __restrict__ lsc, const float* __restrict__ bias,
    u16* __restrict__ wout_g) {
    __shared__ __align__(16) u16 scr[4][6144];  // per wave: v_t[2048] | p_s[4096]

    const int tid = threadIdx.x;
    const int wave = tid >> 6, l = tid & 63, col = l & 15, quad = l >> 4;
    const int job = blockIdx.x * 4 + wave;
    const int h = job >> 11, win = job & 2047;
    u16* const v_t = scr[wave];         // [32 d][64 tok] swz(d&7)
    u16* const p_s = scr[wave] + 2048;  // [64 q][64 k]  swz(i&7)

    #pragma unroll
    for (int it = 0; it < 4; ++it) {
        const int idx = it * 64 + l;
        const int tok = idx & 63, dblk = idx >> 6;
        const u16x8 vv = *(const u16x8*)&wv_g[((size_t)win * 64 + tok) * 256 + h * 32 + dblk * 8];
        #pragma unroll
        for (int j = 0; j < 8; ++j) {
            const int d = dblk * 8 + j;
            v_t[d * 64 + ((((tok >> 3) ^ (d & 7)) << 3) | (tok & 7))] = vv[j];
        }
    }

    const u16* const qbp = gq + (size_t)(win * 8 + h) * 2048;
    const u16* const kbp = gk + (size_t)(win * 8 + h) * 2048;
    bf16x8 aq[4], bk[4];
    #pragma unroll
    for (int mt = 0; mt < 4; ++mt)
        aq[mt] = *(const bf16x8*)&qbp[(mt * 16 + col) * 32 + quad * 8];
    #pragma unroll
    for (int nt = 0; nt < 4; ++nt)
        bk[nt] = *(const bf16x8*)&kbp[(nt * 16 + col) * 32 + quad * 8];

    const f32x4 zero4 = {0.f, 0.f, 0.f, 0.f};
    f32x4 sacc[4][4];
    #pragma unroll
    for (int mt = 0; mt < 4; ++mt)
        #pragma unroll
        for (int nt = 0; nt < 4; ++nt)
            sacc[mt][nt] = __builtin_amdgcn_mfma_f32_16x16x32_bf16(aq[mt], bk[nt], zero4, 0, 0, 0);

    const float ls = expf(fminf(lsc[h], 4.6051701859880914f));
    const float* bh = bias + h * 4096;
    #pragma unroll
    for (int mt = 0; mt < 4; ++mt) {
        #pragma unroll
        for (int r = 0; r < 4; ++r) {
            const int i = mt * 16 + quad * 4 + r;
            float v[4];
            #pragma unroll
            for (int nt = 0; nt < 4; ++nt)
                v[nt] = sacc[mt][nt][r] * ls + bh[i * 64 + nt * 16 + col];
            float mx = fmaxf(fmaxf(v[0], v[1]), fmaxf(v[2], v[3]));
            #pragma unroll
            for (int m = 1; m < 16; m <<= 1) mx = fmaxf(mx, __shfl_xor(mx, m, 64));
            float s = 0.f;
            #pragma unroll
            for (int nt = 0; nt < 4; ++nt) { v[nt] = expf(v[nt] - mx); s += v[nt]; }
            #pragma unroll
            for (int m = 1; m < 16; m <<= 1) s += __shfl_xor(s, m, 64);
            const float inv = 1.0f / s;
            #pragma unroll
            for (int nt = 0; nt < 4; ++nt) sacc[mt][nt][r] = v[nt] * inv;
        }
    }
    #pragma unroll
    for (int mt = 0; mt < 4; ++mt)
        #pragma unroll
        for (int r = 0; r < 4; ++r) {
            const int i = mt * 16 + quad * 4 + r;
            #pragma unroll
            for (int nt = 0; nt < 4; ++nt) {
                const int j = nt * 16 + col;
                p_s[i * 64 + ((((j >> 3) ^ (i & 7)) << 3) | (j & 7))] = f2b(sacc[mt][nt][r]);
            }
        }
    __syncthreads();

    f32x4 oacc[4][2];
    #pragma unroll
    for (int mt = 0; mt < 4; ++mt)
        #pragma unroll
        for (int nt = 0; nt < 2; ++nt) oacc[mt][nt] = zero4;
    #pragma unroll
    for (int kk = 0; kk < 2; ++kk) {
        const int kb = kk * 32 + quad * 8;
        bf16x8 ap[4];
        #pragma unroll
        for (int mt = 0; mt < 4; ++mt) {
            const int i = mt * 16 + col;
            ap[mt] = *(const bf16x8*)&p_s[i * 64 + (((kb >> 3) ^ (i & 7)) << 3)];
        }
        bf16x8 bv[2];
        #pragma unroll
        for (int nt = 0; nt < 2; ++nt) {
            const int d = nt * 16 + col;
            bv[nt] = *(const bf16x8*)&v_t[d * 64 + (((kb >> 3) ^ (d & 7)) << 3)];
        }
        #pragma unroll
        for (int mt = 0; mt < 4; ++mt)
            #pragma unroll
            for (int nt = 0; nt < 2; ++nt)
                oacc[mt][nt] = __builtin_amdgcn_mfma_f32_16x16x32_bf16(ap[mt], bv[nt], oacc[mt][nt], 0, 0, 0);
    }
    #pragma unroll
    for (int mt = 0; mt < 4; ++mt)
        #pragma unroll
        for (int nt = 0; nt < 2; ++nt)
            #pragma unroll
            for (int r = 0; r < 4; ++r) {
                const int t = mt * 16 + quad * 4 + r;
                wout_g[((size_t)win * 64 + t) * 256 + h * 32 + nt * 16 + col] = f2b(oacc[mt][nt][r]);
            }
}

// ---------------------------------------------------------------- proj ----
// R3 verbatim.
__global__ __launch_bounds__(256, 4) void k_proj(
    const u16* __restrict__ wout_g, const u16* __restrict__ wv_g,
    const float* __restrict__ pe_w, const float* __restrict__ pe_b,
    const u16* __restrict__ pjw, const float* __restrict__ pjb,
    float* __restrict__ out) {
    __shared__ __align__(16) u16 y_s[64 * 256];
    const int win = blockIdx.x;
    const int b = win >> 8;
    const int h0 = ((win >> 4) & 15) * 8;
    const int w0 = (win & 15) * 8;
    const int tid = threadIdx.x;
    const int cg = tid & 31, ch = cg * 8;
    const int psub = tid >> 5;

    float pw[9][8];
    #pragma unroll
    for (int j = 0; j < 8; ++j)
        #pragma unroll
        for (int k = 0; k < 9; ++k) pw[k][j] = pe_w[(ch + j) * 9 + k];
    float pb[8];
    #pragma unroll
    for (int j = 0; j < 8; ++j) pb[j] = pe_b[ch + j];

    for (int it = 0; it < 8; ++it) {
        const int p = it * 8 + psub;
        const int gh = h0 + (p >> 3), gw = w0 + (p & 7);
        float a[8];
        {
            const bf16x8 ov = *(const bf16x8*)&wout_g[((size_t)win * 64 + p) * 256 + ch];
            #pragma unroll
            for (int j = 0; j < 8; ++j) a[j] = b2f((u16)ov[j]) + pb[j];
        }
        #pragma unroll
        for (int dy = -1; dy <= 1; ++dy)
            #pragma unroll
            for (int dx = -1; dx <= 1; ++dx) {
                const int hh = gh + dy, ww2 = gw + dx;
                if (hh < 0 || hh >= 128 || ww2 < 0 || ww2 >= 128) continue;
                const int nwin = b * 256 + (hh >> 3) * 16 + (ww2 >> 3);
                const int ntk = (hh & 7) * 8 + (ww2 & 7);
                const bf16x8 vv = *(const bf16x8*)&wv_g[((size_t)nwin * 64 + ntk) * 256 + ch];
                const int k = (dy + 1) * 3 + (dx + 1);
                #pragma unroll
                for (int j = 0; j < 8; ++j) a[j] += b2f((u16)vv[j]) * pw[k][j];
            }
        u16x8 tmp;
        #pragma unroll
        for (int j = 0; j < 8; ++j) tmp[j] = f2b(a[j]);
        *(u16x8*)&y_s[p * 256 + (((ch >> 3) ^ (p & 7)) << 3)] = tmp;
    }
    __syncthreads();

    const int wave = tid >> 6, l = tid & 63;
    const int col = l & 15, quad = l >> 4;
    const f32x4 zero4 = {0.f, 0.f, 0.f, 0.f};
    f32x4 macc[4][4];
    #pragma unroll
    for (int mt = 0; mt < 4; ++mt)
        #pragma unroll
        for (int nt = 0; nt < 4; ++nt) macc[mt][nt] = zero4;
    const int ob = wave * 64;
    for (int kk = 0; kk < 8; ++kk) {
        const int cb = kk * 32 + quad * 8;
        bf16x8 aw[4], by[4];
        #pragma unroll
        for (int mt = 0; mt < 4; ++mt)
            aw[mt] = *(const bf16x8*)&pjw[(size_t)(ob + mt * 16 + col) * 256 + cb];
        #pragma unroll
        for (int nt = 0; nt < 4; ++nt) {
            const int p = nt * 16 + col;
            by[nt] = *(const bf16x8*)&y_s[p * 256 + (((cb >> 3) ^ (p & 7)) << 3)];
        }
        #pragma unroll
        for (int mt = 0; mt < 4; ++mt)
            #pragma unroll
            for (int nt = 0; nt < 4; ++nt)
                macc[mt][nt] = __builtin_amdgcn_mfma_f32_16x16x32_bf16(aw[mt], by[nt], macc[mt][nt], 0, 0, 0);
    }
    #pragma unroll
    for (int mt = 0; mt < 4; ++mt)
        #pragma unroll
        for (int r = 0; r < 4; ++r) {
            const int o = ob + mt * 16 + quad * 4 + r;
            const float pbv = pjb[o];
            #pragma unroll
            for (int nt = 0; nt < 4; ++nt) {
                const int p = nt * 16 + col;
                out[(((size_t)b * 256 + o) * 128 + h0 + (p >> 3)) * 128 + w0 + (p & 7)] =
                    macc[mt][nt][r] + pbv;
            }
        }
}

// -------------------------------------------------------------- launch ----
extern "C" void kernel_launch(void* const* d_in, const int* in_sizes, int n_in,
                              void* d_out, int out_size, void* d_ws, size_t ws_size,
                              hipStream_t stream) {
    const float* x    = (const float*)d_in[0];
    const float* qkvw = (const float*)d_in[1];
    const float* qkvb = (const float*)d_in[2];
    const float* pjw  = (const float*)d_in[3];
    const float* pjb  = (const float*)d_in[4];
    const float* pew  = (const float*)d_in[5];
    const float* peb  = (const float*)d_in[6];
    const float* lsc  = (const float*)d_in[7];
    const float* w1   = (const float*)d_in[8];
    const float* b1   = (const float*)d_in[9];
    const float* w2   = (const float*)d_in[10];

    char* ws = (char*)d_ws;
    u16* wv_b    = (u16*)(ws);                                    // 64 MiB
    u16* wout_b  = (u16*)(ws + (64ull << 20));                    // 64 MiB
    u16* qkvwb   = (u16*)(ws + (128ull << 20));                   // 384 KiB
    u16* pjwb    = (u16*)(ws + (128ull << 20) + 393216);          // 128 KiB
    float* bias  = (float*)(ws + (128ull << 20) + 393216 + 131072); // 128 KiB
    float* bt    = (float*)(ws + (128ull << 20) + 393216 + 262144); // 7.2 KiB

    // q/k scratch lives inside d_out (134.2 MB = exactly 2 x 64 MiB bf16);
    // dead before k_proj fully overwrites d_out.
    u16* gq = (u16*)d_out;
    u16* gk = gq + 33554432u;

    hipLaunchKernelGGL(k_prep, dim3(768), dim3(256), 0, stream, qkvw, pjw, qkvwb, pjwb);
    hipLaunchKernelGGL(k_cpb,  dim3(1),   dim3(256), 0, stream, w1, b1, w2, bt);
    hipLaunchKernelGGL(k_bias, dim3(16),  dim3(256), 0, stream, bt, bias);
    hipLaunchKernelGGL(k_qkv,  dim3(6144), dim3(256), 0, stream,
                       x, qkvwb, qkvb, gq, gk, wv_b);
    hipLaunchKernelGGL(k_attn3, dim3(4096), dim3(256), 0, stream,
                       gq, gk, wv_b, lsc, bias, wout_b);
    hipLaunchKernelGGL(k_proj, dim3(2048), dim3(256), 0, stream,
                       wout_b, wv_b, pew, peb, pjwb, pjb, (float*)d_out);
}

// Round 5
// 476.329 us; speedup vs baseline: 1.1954x; 1.1954x over previous
//
#include <hip/hip_runtime.h>

typedef unsigned short u16;
typedef unsigned int u32;
typedef short bf16x8 __attribute__((ext_vector_type(8)));
typedef float f32x4 __attribute__((ext_vector_type(4)));
typedef unsigned short u16x8 __attribute__((ext_vector_type(8)));

#define DEVFN static __device__ __forceinline__

DEVFN u16 f2b(float f) {
    u32 u = __builtin_bit_cast(u32, f);
    u += 0x7FFFu + ((u >> 16) & 1u);
    return (u16)(u >> 16);
}
DEVFN float b2f(u16 h) {
    u32 u = ((u32)h) << 16;
    return __builtin_bit_cast(float, u);
}

// ---------------------------------------------------------------- prep ----
__global__ void k_prep(const float* __restrict__ qkvw, const float* __restrict__ pjw,
                       u16* __restrict__ qkvwb, u16* __restrict__ pjwb) {
    int id = blockIdx.x * 256 + threadIdx.x;
    if (id < 196608) qkvwb[id] = f2b(qkvw[id]);
    if (id < 65536)  pjwb[id]  = f2b(pjw[id]);
}

__global__ void k_cpb(const float* __restrict__ w1, const float* __restrict__ b1,
                      const float* __restrict__ w2, float* __restrict__ bt) {
    int p = threadIdx.x;
    if (p >= 225) return;
    int d0 = p / 15, d1 = p % 15;
    float v0 = (float)(d0 - 7) * (8.0f / 7.0f);
    float v1 = (float)(d1 - 7) * (8.0f / 7.0f);
    float t0 = copysignf(log2f(fabsf(v0) + 1.0f) * (1.0f / 3.0f), v0);
    float t1 = copysignf(log2f(fabsf(v1) + 1.0f) * (1.0f / 3.0f), v1);
    float s[8] = {0.f, 0.f, 0.f, 0.f, 0.f, 0.f, 0.f, 0.f};
    for (int d = 0; d < 256; ++d) {
        float h = t0 * w1[2 * d] + t1 * w1[2 * d + 1] + b1[d];
        h = fmaxf(h, 0.0f);
        #pragma unroll
        for (int hh = 0; hh < 8; ++hh) s[hh] += h * w2[hh * 256 + d];
    }
    #pragma unroll
    for (int hh = 0; hh < 8; ++hh) bt[p * 8 + hh] = s[hh];
}

__global__ void k_bias(const float* __restrict__ bt, float* __restrict__ bias) {
    int id = blockIdx.x * 256 + threadIdx.x;  // 4096 = 64*64, i=q row, j=k col
    int i = id >> 6, j = id & 63;
    int d0 = (i >> 3) - (j >> 3) + 7;
    int d1 = (i & 7) - (j & 7) + 7;
    int p = d0 * 15 + d1;
    #pragma unroll
    for (int h = 0; h < 8; ++h)
        bias[h * 4096 + id] = 16.0f / (1.0f + expf(-bt[p * 8 + h]));
}

// ---------------------------------------------------------------- qkv -----
// Row-structured GEMM: block = (image row, which, och-half). M=128 tokens
// (one row), N=128 och, K=256 chunked at 64 with double-buffered LDS.
// __launch_bounds__(256,3): VGPR cap ~170 so acc[4][4] + float4 st[8] stay
// in registers (256,4's 128-cap spilled st -> scratch: VGPR=64, WRITE 2.1x).
__global__ __launch_bounds__(256, 3) void k_qkv(
    const float* __restrict__ x, const u16* __restrict__ qkvw,
    const float* __restrict__ qkvb,
    u16* __restrict__ gq, u16* __restrict__ gk, u16* __restrict__ wv_g) {
    __shared__ __align__(16) u16 Xs[2][8192];  // [128 tok][64 ch] swizzled

    // XCD-aware job mapping: all 6 (which,half) blocks of a row on one XCD.
    const int bid = blockIdx.x;                 // 6144 = 8 xcd * 128 rowblk * 6 ny
    const int xcd = bid & 7;
    const int idx = bid >> 3;                   // 0..767
    const int ny = idx % 6;
    const int rowblk = xcd * 128 + idx / 6;     // 0..1023
    const int b = rowblk >> 7, row = rowblk & 127;
    const int which = ny >> 1, half = ny & 1;

    const int tid = threadIdx.x;
    const int wave = tid >> 6, l = tid & 63, col = l & 15, quad = l >> 4;
    const int th = wave >> 1;                   // token half (64 tok)
    const int oq = wave & 1;                    // och quarter
    const int obase = half * 128 + oq * 64;     // och base within `which` (0..255)

    // weight rows + bias for this wave's 4 n-tiles (original qkvw layout)
    int orow[4];
    float bq[4];
    #pragma unroll
    for (int nt = 0; nt < 4; ++nt) {
        const int oo = obase + nt * 16 + col;   // 0..255 within which
        orow[nt] = (oo >> 5) * 96 + which * 32 + (oo & 31);
        bq[nt] = qkvb[orow[nt]];
    }

    const int tc = tid >> 5;                    // 0..7: 8-ch sub-chunk
    const int tw = (tid & 31) * 4;              // token base (4 consecutive)
    const float* xbase = x + ((size_t)b * 256 * 128 + row) * 128;

    f32x4 acc[4][4];
    #pragma unroll
    for (int i = 0; i < 4; ++i)
        #pragma unroll
        for (int j = 0; j < 4; ++j) acc[i][j] = f32x4{0.f, 0.f, 0.f, 0.f};

    float4 st[8];
    auto stage_load = [&](int c) {
        #pragma unroll
        for (int j = 0; j < 8; ++j)
            st[j] = *(const float4*)(xbase + (size_t)(c * 64 + tc * 8 + j) * 16384 + tw);
    };
    // transpose via named members only (no address-of-register casts -> no spill)
    auto stage_write = [&](int buf) {
        u16x8 v0, v1, v2, v3;
        #pragma unroll
        for (int j = 0; j < 8; ++j) {
            v0[j] = f2b(st[j].x);
            v1[j] = f2b(st[j].y);
            v2[j] = f2b(st[j].z);
            v3[j] = f2b(st[j].w);
        }
        const int base7 = tid & 31;             // (tw+i)>>2 for i<4
        const int s0 = tc ^ ((base7 ^ (tw + 0)) & 7);
        const int s1 = tc ^ ((base7 ^ (tw + 1)) & 7);
        const int s2 = tc ^ ((base7 ^ (tw + 2)) & 7);
        const int s3 = tc ^ ((base7 ^ (tw + 3)) & 7);
        *(u16x8*)&Xs[buf][(tw + 0) * 64 + (s0 << 3)] = v0;
        *(u16x8*)&Xs[buf][(tw + 1) * 64 + (s1 << 3)] = v1;
        *(u16x8*)&Xs[buf][(tw + 2) * 64 + (s2 << 3)] = v2;
        *(u16x8*)&Xs[buf][(tw + 3) * 64 + (s3 << 3)] = v3;
    };
    auto gemm = [&](int c, int buf) {
        #pragma unroll
        for (int kk = 0; kk < 2; ++kk) {
            const int cb = c * 64 + kk * 32 + quad * 8;   // global ch base
            const int lchunk = kk * 4 + quad;             // local 8-ch chunk
            bf16x8 bw[4];
            #pragma unroll
            for (int nt = 0; nt < 4; ++nt)
                bw[nt] = *(const bf16x8*)&qkvw[(size_t)orow[nt] * 256 + cb];
            bf16x8 af[4];
            #pragma unroll
            for (int mt = 0; mt < 4; ++mt) {
                const int tok = th * 64 + mt * 16 + col;
                const int slot = lchunk ^ (((tok >> 2) ^ tok) & 7);
                af[mt] = *(const bf16x8*)&Xs[buf][tok * 64 + (slot << 3)];
            }
            #pragma unroll
            for (int mt = 0; mt < 4; ++mt)
                #pragma unroll
                for (int nt = 0; nt < 4; ++nt)
                    acc[mt][nt] = __builtin_amdgcn_mfma_f32_16x16x32_bf16(
                        af[mt], bw[nt], acc[mt][nt], 0, 0, 0);
        }
    };

    stage_load(0);
    stage_write(0);
    __syncthreads();
    for (int c = 0; c < 4; ++c) {
        if (c < 3) stage_load(c + 1);      // issue early (T14)
        gemm(c, c & 1);
        if (c < 3) stage_write((c + 1) & 1);  // write late
        __syncthreads();
    }

    // epilogue: +bias; cosine-norm (q/k) over d via 16-lane shfl_xor (R1 math)
    const int hA = obase >> 5;  // first of the two heads this wave covers
    #pragma unroll
    for (int mt = 0; mt < 4; ++mt) {
        float v0[4], v1[4], v2[4], v3[4];
        #pragma unroll
        for (int r = 0; r < 4; ++r) {
            v0[r] = acc[mt][0][r] + bq[0];
            v1[r] = acc[mt][1][r] + bq[1];
            v2[r] = acc[mt][2][r] + bq[2];
            v3[r] = acc[mt][3][r] + bq[3];
        }
        if (which < 2) {
            float s0[4], s1[4];
            #pragma unroll
            for (int r = 0; r < 4; ++r) {
                s0[r] = v0[r] * v0[r] + v1[r] * v1[r];
                s1[r] = v2[r] * v2[r] + v3[r] * v3[r];
            }
            #pragma unroll
            for (int m = 1; m < 16; m <<= 1) {
                #pragma unroll
                for (int r = 0; r < 4; ++r) {
                    s0[r] += __shfl_xor(s0[r], m, 64);
                    s1[r] += __shfl_xor(s1[r], m, 64);
                }
            }
            #pragma unroll
            for (int r = 0; r < 4; ++r) {
                const float i0 = 1.0f / fmaxf(sqrtf(s0[r]), 1e-12f);
                const float i1 = 1.0f / fmaxf(sqrtf(s1[r]), 1e-12f);
                v0[r] *= i0; v1[r] *= i0;
                v2[r] *= i1; v3[r] *= i1;
            }
        }
        #pragma unroll
        for (int r = 0; r < 4; ++r) {
            const int w = th * 64 + mt * 16 + quad * 4 + r;      // token in row
            const int win = b * 256 + (row >> 3) * 16 + (w >> 3);
            const int tk = (row & 7) * 8 + (w & 7);
            if (which == 2) {
                u16* wvp = wv_g + ((size_t)win * 64 + tk) * 256 + obase;
                wvp[col]      = f2b(v0[r]);
                wvp[col + 16] = f2b(v1[r]);
                wvp[col + 32] = f2b(v2[r]);
                wvp[col + 48] = f2b(v3[r]);
            } else {
                u16* G = (which == 0) ? gq : gk;
                const size_t baseA = ((size_t)(win * 8 + hA) * 64 + tk) * 32;
                const size_t baseB = ((size_t)(win * 8 + hA + 1) * 64 + tk) * 32;
                G[baseA + col]      = f2b(v0[r]);
                G[baseA + col + 16] = f2b(v1[r]);
                G[baseB + col]      = f2b(v2[r]);
                G[baseB + col + 16] = f2b(v3[r]);
            }
        }
    }
}

// ---------------------------------------------------------------- attn ----
// R3 verbatim: one wave = one (win, head); 4 jobs per 256-thr block.
__global__ __launch_bounds__(256, 3) void k_attn3(
    const u16* __restrict__ gq, const u16* __restrict__ gk,
    const u16* __restrict__ wv_g,
    const float* __restrict__ lsc, const float* __restrict__ bias,
    u16* __restrict__ wout_g) {
    __shared__ __align__(16) u16 scr[4][6144];  // per wave: v_t[2048] | p_s[4096]

    const int tid = threadIdx.x;
    const int wave = tid >> 6, l = tid & 63, col = l & 15, quad = l >> 4;
    const int job = blockIdx.x * 4 + wave;
    const int h = job >> 11, win = job & 2047;
    u16* const v_t = scr[wave];         // [32 d][64 tok] swz(d&7)
    u16* const p_s = scr[wave] + 2048;  // [64 q][64 k]  swz(i&7)

    #pragma unroll
    for (int it = 0; it < 4; ++it) {
        const int idx = it * 64 + l;
        const int tok = idx & 63, dblk = idx >> 6;
        const u16x8 vv = *(const u16x8*)&wv_g[((size_t)win * 64 + tok) * 256 + h * 32 + dblk * 8];
        #pragma unroll
        for (int j = 0; j < 8; ++j) {
            const int d = dblk * 8 + j;
            v_t[d * 64 + ((((tok >> 3) ^ (d & 7)) << 3) | (tok & 7))] = vv[j];
        }
    }

    const u16* const qbp = gq + (size_t)(win * 8 + h) * 2048;
    const u16* const kbp = gk + (size_t)(win * 8 + h) * 2048;
    bf16x8 aq[4], bk[4];
    #pragma unroll
    for (int mt = 0; mt < 4; ++mt)
        aq[mt] = *(const bf16x8*)&qbp[(mt * 16 + col) * 32 + quad * 8];
    #pragma unroll
    for (int nt = 0; nt < 4; ++nt)
        bk[nt] = *(const bf16x8*)&kbp[(nt * 16 + col) * 32 + quad * 8];

    const f32x4 zero4 = {0.f, 0.f, 0.f, 0.f};
    f32x4 sacc[4][4];
    #pragma unroll
    for (int mt = 0; mt < 4; ++mt)
        #pragma unroll
        for (int nt = 0; nt < 4; ++nt)
            sacc[mt][nt] = __builtin_amdgcn_mfma_f32_16x16x32_bf16(aq[mt], bk[nt], zero4, 0, 0, 0);

    const float ls = expf(fminf(lsc[h], 4.6051701859880914f));
    const float* bh = bias + h * 4096;
    #pragma unroll
    for (int mt = 0; mt < 4; ++mt) {
        #pragma unroll
        for (int r = 0; r < 4; ++r) {
            const int i = mt * 16 + quad * 4 + r;
            float v[4];
            #pragma unroll
            for (int nt = 0; nt < 4; ++nt)
                v[nt] = sacc[mt][nt][r] * ls + bh[i * 64 + nt * 16 + col];
            float mx = fmaxf(fmaxf(v[0], v[1]), fmaxf(v[2], v[3]));
            #pragma unroll
            for (int m = 1; m < 16; m <<= 1) mx = fmaxf(mx, __shfl_xor(mx, m, 64));
            float s = 0.f;
            #pragma unroll
            for (int nt = 0; nt < 4; ++nt) { v[nt] = expf(v[nt] - mx); s += v[nt]; }
            #pragma unroll
            for (int m = 1; m < 16; m <<= 1) s += __shfl_xor(s, m, 64);
            const float inv = 1.0f / s;
            #pragma unroll
            for (int nt = 0; nt < 4; ++nt) sacc[mt][nt][r] = v[nt] * inv;
        }
    }
    #pragma unroll
    for (int mt = 0; mt < 4; ++mt)
        #pragma unroll
        for (int r = 0; r < 4; ++r) {
            const int i = mt * 16 + quad * 4 + r;
            #pragma unroll
            for (int nt = 0; nt < 4; ++nt) {
                const int j = nt * 16 + col;
                p_s[i * 64 + ((((j >> 3) ^ (i & 7)) << 3) | (j & 7))] = f2b(sacc[mt][nt][r]);
            }
        }
    __syncthreads();

    f32x4 oacc[4][2];
    #pragma unroll
    for (int mt = 0; mt < 4; ++mt)
        #pragma unroll
        for (int nt = 0; nt < 2; ++nt) oacc[mt][nt] = zero4;
    #pragma unroll
    for (int kk = 0; kk < 2; ++kk) {
        const int kb = kk * 32 + quad * 8;
        bf16x8 ap[4];
        #pragma unroll
        for (int mt = 0; mt < 4; ++mt) {
            const int i = mt * 16 + col;
            ap[mt] = *(const bf16x8*)&p_s[i * 64 + (((kb >> 3) ^ (i & 7)) << 3)];
        }
        bf16x8 bv[2];
        #pragma unroll
        for (int nt = 0; nt < 2; ++nt) {
            const int d = nt * 16 + col;
            bv[nt] = *(const bf16x8*)&v_t[d * 64 + (((kb >> 3) ^ (d & 7)) << 3)];
        }
        #pragma unroll
        for (int mt = 0; mt < 4; ++mt)
            #pragma unroll
            for (int nt = 0; nt < 2; ++nt)
                oacc[mt][nt] = __builtin_amdgcn_mfma_f32_16x16x32_bf16(ap[mt], bv[nt], oacc[mt][nt], 0, 0, 0);
    }
    #pragma unroll
    for (int mt = 0; mt < 4; ++mt)
        #pragma unroll
        for (int nt = 0; nt < 2; ++nt)
            #pragma unroll
            for (int r = 0; r < 4; ++r) {
                const int t = mt * 16 + quad * 4 + r;
                wout_g[((size_t)win * 64 + t) * 256 + h * 32 + nt * 16 + col] = f2b(oacc[mt][nt][r]);
            }
}

// ---------------------------------------------------------------- proj ----
// R3 verbatim.
__global__ __launch_bounds__(256, 4) void k_proj(
    const u16* __restrict__ wout_g, const u16* __restrict__ wv_g,
    const float* __restrict__ pe_w, const float* __restrict__ pe_b,
    const u16* __restrict__ pjw, const float* __restrict__ pjb,
    float* __restrict__ out) {
    __shared__ __align__(16) u16 y_s[64 * 256];
    const int win = blockIdx.x;
    const int b = win >> 8;
    const int h0 = ((win >> 4) & 15) * 8;
    const int w0 = (win & 15) * 8;
    const int tid = threadIdx.x;
    const int cg = tid & 31, ch = cg * 8;
    const int psub = tid >> 5;

    float pw[9][8];
    #pragma unroll
    for (int j = 0; j < 8; ++j)
        #pragma unroll
        for (int k = 0; k < 9; ++k) pw[k][j] = pe_w[(ch + j) * 9 + k];
    float pb[8];
    #pragma unroll
    for (int j = 0; j < 8; ++j) pb[j] = pe_b[ch + j];

    for (int it = 0; it < 8; ++it) {
        const int p = it * 8 + psub;
        const int gh = h0 + (p >> 3), gw = w0 + (p & 7);
        float a[8];
        {
            const bf16x8 ov = *(const bf16x8*)&wout_g[((size_t)win * 64 + p) * 256 + ch];
            #pragma unroll
            for (int j = 0; j < 8; ++j) a[j] = b2f((u16)ov[j]) + pb[j];
        }
        #pragma unroll
        for (int dy = -1; dy <= 1; ++dy)
            #pragma unroll
            for (int dx = -1; dx <= 1; ++dx) {
                const int hh = gh + dy, ww2 = gw + dx;
                if (hh < 0 || hh >= 128 || ww2 < 0 || ww2 >= 128) continue;
                const int nwin = b * 256 + (hh >> 3) * 16 + (ww2 >> 3);
                const int ntk = (hh & 7) * 8 + (ww2 & 7);
                const bf16x8 vv = *(const bf16x8*)&wv_g[((size_t)nwin * 64 + ntk) * 256 + ch];
                const int k = (dy + 1) * 3 + (dx + 1);
                #pragma unroll
                for (int j = 0; j < 8; ++j) a[j] += b2f((u16)vv[j]) * pw[k][j];
            }
        u16x8 tmp;
        #pragma unroll
        for (int j = 0; j < 8; ++j) tmp[j] = f2b(a[j]);
        *(u16x8*)&y_s[p * 256 + (((ch >> 3) ^ (p & 7)) << 3)] = tmp;
    }
    __syncthreads();

    const int wave = tid >> 6, l = tid & 63;
    const int col = l & 15, quad = l >> 4;
    const f32x4 zero4 = {0.f, 0.f, 0.f, 0.f};
    f32x4 macc[4][4];
    #pragma unroll
    for (int mt = 0; mt < 4; ++mt)
        #pragma unroll
        for (int nt = 0; nt < 4; ++nt) macc[mt][nt] = zero4;
    const int ob = wave * 64;
    for (int kk = 0; kk < 8; ++kk) {
        const int cb = kk * 32 + quad * 8;
        bf16x8 aw[4], by[4];
        #pragma unroll
        for (int mt = 0; mt < 4; ++mt)
            aw[mt] = *(const bf16x8*)&pjw[(size_t)(ob + mt * 16 + col) * 256 + cb];
        #pragma unroll
        for (int nt = 0; nt < 4; ++nt) {
            const int p = nt * 16 + col;
            by[nt] = *(const bf16x8*)&y_s[p * 256 + (((cb >> 3) ^ (p & 7)) << 3)];
        }
        #pragma unroll
        for (int mt = 0; mt < 4; ++mt)
            #pragma unroll
            for (int nt = 0; nt < 4; ++nt)
                macc[mt][nt] = __builtin_amdgcn_mfma_f32_16x16x32_bf16(aw[mt], by[nt], macc[mt][nt], 0, 0, 0);
    }
    #pragma unroll
    for (int mt = 0; mt < 4; ++mt)
        #pragma unroll
        for (int r = 0; r < 4; ++r) {
            const int o = ob + mt * 16 + quad * 4 + r;
            const float pbv = pjb[o];
            #pragma unroll
            for (int nt = 0; nt < 4; ++nt) {
                const int p = nt * 16 + col;
                out[(((size_t)b * 256 + o) * 128 + h0 + (p >> 3)) * 128 + w0 + (p & 7)] =
                    macc[mt][nt][r] + pbv;
            }
        }
}

// -------------------------------------------------------------- launch ----
extern "C" void kernel_launch(void* const* d_in, const int* in_sizes, int n_in,
                              void* d_out, int out_size, void* d_ws, size_t ws_size,
                              hipStream_t stream) {
    const float* x    = (const float*)d_in[0];
    const float* qkvw = (const float*)d_in[1];
    const float* qkvb = (const float*)d_in[2];
    const float* pjw  = (const float*)d_in[3];
    const float* pjb  = (const float*)d_in[4];
    const float* pew  = (const float*)d_in[5];
    const float* peb  = (const float*)d_in[6];
    const float* lsc  = (const float*)d_in[7];
    const float* w1   = (const float*)d_in[8];
    const float* b1   = (const float*)d_in[9];
    const float* w2   = (const float*)d_in[10];

    char* ws = (char*)d_ws;
    u16* wv_b    = (u16*)(ws);                                    // 64 MiB
    u16* wout_b  = (u16*)(ws + (64ull << 20));                    // 64 MiB
    u16* qkvwb   = (u16*)(ws + (128ull << 20));                   // 384 KiB
    u16* pjwb    = (u16*)(ws + (128ull << 20) + 393216);          // 128 KiB
    float* bias  = (float*)(ws + (128ull << 20) + 393216 + 131072); // 128 KiB
    float* bt    = (float*)(ws + (128ull << 20) + 393216 + 262144); // 7.2 KiB

    // q/k scratch lives inside d_out (134.2 MB = exactly 2 x 64 MiB bf16);
    // dead before k_proj fully overwrites d_out.
    u16* gq = (u16*)d_out;
    u16* gk = gq + 33554432u;

    hipLaunchKernelGGL(k_prep, dim3(768), dim3(256), 0, stream, qkvw, pjw, qkvwb, pjwb);
    hipLaunchKernelGGL(k_cpb,  dim3(1),   dim3(256), 0, stream, w1, b1, w2, bt);
    hipLaunchKernelGGL(k_bias, dim3(16),  dim3(256), 0, stream, bt, bias);
    hipLaunchKernelGGL(k_qkv,  dim3(6144), dim3(256), 0, stream,
                       x, qkvwb, qkvb, gq, gk, wv_b);
    hipLaunchKernelGGL(k_attn3, dim3(4096), dim3(256), 0, stream,
                       gq, gk, wv_b, lsc, bias, wout_b);
    hipLaunchKernelGGL(k_proj, dim3(2048), dim3(256), 0, stream,
                       wout_b, wv_b, pew, peb, pjwb, pjb, (float*)d_out);
}